// Round 7
// baseline (26.873 us; speedup 1.0000x reference)
//
#include <hip/hip_runtime.h>
#include <hip/hip_bf16.h>

// N=4096, M=128, R=16, W=64, NG=1024, delta = 1/128 exactly.
// out[r][w] = sum_m red[r,m]*(c4[idx_m,w]*x0_m + c5[idx_m,w])
//           = sum_{k'=0..255} A'[r,k'] B'[k',w]        (K'=256, interleaved pairs)
//   A'[r,2m]   = bf16(red[r,m]*x0_m),  A'[r,2m+1] = bf16(red[r,m])
//   B'[2m,w]   = bf16(c4[idx_m,w]),    B'[2m+1,w] = bf16(c5[idx_m,w])
// tbl word (c5<<16)|c4 IS the packed (B'[2m,w],B'[2m+1,w]) pair -> zero VALU on B path.

constexpr int MM = 128;
constexpr int RR = 16;
constexpr int WW = 64;
constexpr int NG = 1024;

using f32x4  = __attribute__((ext_vector_type(4))) float;
using bf16x8 = __attribute__((ext_vector_type(8))) __bf16;

__device__ __forceinline__ unsigned pack_bf16(float lo, float hi) {
    __hip_bfloat162 p = __float22bfloat162_rn(make_float2(lo, hi));
    unsigned r; __builtin_memcpy(&r, &p, sizeof(r));   // v_cvt_pk_bf16_f32
    return r;
}

// ---- prepass: tbl[g*64 + w] = (bf16(c5)<<16) | bf16(c4) ----
__global__ __launch_bounds__(256)
void build_tbl_kernel(const float* __restrict__ poly, unsigned* __restrict__ tbl) {
    const int t = blockIdx.x * 256 + threadIdx.x;   // 65536
    const int g = t >> 6, w = t & 63;
    tbl[t] = pack_bf16(poly[g * 384 + 256 + w], poly[g * 384 + 320 + w]);
}

template<bool USE_TBL>
__global__ __launch_bounds__(256, 4)
void embed_mfma_kernel(const float* __restrict__ x,
                       const unsigned* __restrict__ tbl,
                       const float* __restrict__ poly,
                       const float* __restrict__ red,
                       float* __restrict__ out)
{
    // uint4 block b holds k' = 8b..8b+7 (i.e. m = 4b..4b+3, both coeffs each).
    __shared__ uint4 eB[WW][32];   // eB[w][b ^ (w&7)]   32 KB
    __shared__ uint4 rA[RR][32];   // rA[r][b ^ (r&7)]    8 KB

    const int n   = blockIdx.x;
    const int t   = threadIdx.x;
    const int wt  = t >> 6;          // wave id
    const int q   = (t >> 4) & 3;    // == (lane>>4)
    const int c16 = t & 15;          // == lane&15

    const int mb8 = wt * 4 + q;      // owned m-block of 8: m = mb8*8 .. +7
    const int m0  = mb8 * 8;

    // ---- loads (issued first; all coalesced / L1-broadcast) ----
    const float* xp = x + (size_t)n * MM + m0;
    const float4 xv0 = *(const float4*)xp;
    const float4 xv1 = *(const float4*)(xp + 4);
    const float* rp = red + (size_t)n * (RR * MM) + c16 * MM + m0;
    const float4 rv0 = *(const float4*)rp;
    const float4 rv1 = *(const float4*)(rp + 4);

    const float xs[8] = {xv0.x, xv0.y, xv0.z, xv0.w, xv1.x, xv1.y, xv1.z, xv1.w};
    const float rs[8] = {rv0.x, rv0.y, rv0.z, rv0.w, rv1.x, rv1.y, rv1.z, rv1.w};
    int ii[8]; float x0[8];
#pragma unroll
    for (int j = 0; j < 8; ++j) {
        ii[j] = (int)(xs[j] * 128.0f);
        x0[j] = xs[j] - (float)ii[j] * 0.0078125f;
    }

    unsigned gc[8][4];   // gc[j][c] = packed (c4,c5) for (m0+j, w=c16*4+c)

    if (USE_TBL) {
        // coalesced gather: per instr, 4 tbl rows x 2 lines = 8 line-requests/wave
        uint4 g[8];
#pragma unroll
        for (int j = 0; j < 8; ++j)
            g[j] = *(const uint4*)(tbl + (size_t)ii[j] * 64 + c16 * 4);

        // ---- A' staging while gathers are in flight ----
        {
            uint4 a0, a1;
            a0.x = pack_bf16(rs[0] * x0[0], rs[0]);
            a0.y = pack_bf16(rs[1] * x0[1], rs[1]);
            a0.z = pack_bf16(rs[2] * x0[2], rs[2]);
            a0.w = pack_bf16(rs[3] * x0[3], rs[3]);
            a1.x = pack_bf16(rs[4] * x0[4], rs[4]);
            a1.y = pack_bf16(rs[5] * x0[5], rs[5]);
            a1.z = pack_bf16(rs[6] * x0[6], rs[6]);
            a1.w = pack_bf16(rs[7] * x0[7], rs[7]);
            const int sa = c16 & 7;
            rA[c16][(mb8 * 2)     ^ sa] = a0;
            rA[c16][(mb8 * 2 + 1) ^ sa] = a1;
        }

#pragma unroll
        for (int j = 0; j < 8; ++j) {
            gc[j][0] = g[j].x; gc[j][1] = g[j].y; gc[j][2] = g[j].z; gc[j][3] = g[j].w;
        }
    } else {
        {
            uint4 a0, a1;
            a0.x = pack_bf16(rs[0] * x0[0], rs[0]);
            a0.y = pack_bf16(rs[1] * x0[1], rs[1]);
            a0.z = pack_bf16(rs[2] * x0[2], rs[2]);
            a0.w = pack_bf16(rs[3] * x0[3], rs[3]);
            a1.x = pack_bf16(rs[4] * x0[4], rs[4]);
            a1.y = pack_bf16(rs[5] * x0[5], rs[5]);
            a1.z = pack_bf16(rs[6] * x0[6], rs[6]);
            a1.w = pack_bf16(rs[7] * x0[7], rs[7]);
            const int sa = c16 & 7;
            rA[c16][(mb8 * 2)     ^ sa] = a0;
            rA[c16][(mb8 * 2 + 1) ^ sa] = a1;
        }
#pragma unroll
        for (int j = 0; j < 8; ++j) {
            const float* pc = poly + (size_t)ii[j] * 384 + c16 * 4;
            const float4 c4 = *(const float4*)(pc + 256);
            const float4 c5 = *(const float4*)(pc + 320);
            gc[j][0] = pack_bf16(c4.x, c5.x);
            gc[j][1] = pack_bf16(c4.y, c5.y);
            gc[j][2] = pack_bf16(c4.z, c5.z);
            gc[j][3] = pack_bf16(c4.w, c5.w);
        }
    }

    // ---- B' writes: pure register renaming, 8x ds_write_b128 ----
#pragma unroll
    for (int c = 0; c < 4; ++c) {
        const int w  = c16 * 4 + c;
        const int sw = w & 7;
        uint4 v0, v1;
        v0.x = gc[0][c]; v0.y = gc[1][c]; v0.z = gc[2][c]; v0.w = gc[3][c];
        v1.x = gc[4][c]; v1.y = gc[5][c]; v1.z = gc[6][c]; v1.w = gc[7][c];
        eB[w][(mb8 * 2)     ^ sw] = v0;
        eB[w][(mb8 * 2 + 1) ^ sw] = v1;
    }

    __syncthreads();

    // ---- MFMA: 8 chained 16x16x32 over K'=256; wave wt -> out[0:16][wt*16..+16] ----
    const int sa   = c16 & 7;
    const int rowb = wt * 16 + c16;          // rowb&7 == sa
    f32x4 acc = {0.f, 0.f, 0.f, 0.f};
#pragma unroll
    for (int kc = 0; kc < 8; ++kc) {
        const int bk = kc * 4 + q;
        const uint4 av = rA[c16][bk ^ sa];
        const uint4 bv = eB[rowb][bk ^ sa];
        const bf16x8 afr = __builtin_bit_cast(bf16x8, av);
        const bf16x8 bfr = __builtin_bit_cast(bf16x8, bv);
        acc = __builtin_amdgcn_mfma_f32_16x16x32_bf16(afr, bfr, acc, 0, 0, 0);
    }

    // C/D layout: col = lane&15 (w), row = (lane>>4)*4 + reg (r)
    float* op = out + (size_t)n * (RR * WW) + (size_t)(q * 4) * WW + rowb;
    op[0 * WW] = acc[0];
    op[1 * WW] = acc[1];
    op[2 * WW] = acc[2];
    op[3 * WW] = acc[3];
}

extern "C" void kernel_launch(void* const* d_in, const int* in_sizes, int n_in,
                              void* d_out, int out_size, void* d_ws, size_t ws_size,
                              hipStream_t stream) {
    const float* x    = (const float*)d_in[0];
    const float* poly = (const float*)d_in[1];
    const float* red  = (const float*)d_in[2];
    float* out = (float*)d_out;
    const int N = in_sizes[0] / MM;   // 4096

    if (ws_size >= (size_t)(NG * WW * sizeof(unsigned))) {
        unsigned* tbl = (unsigned*)d_ws;
        build_tbl_kernel<<<(NG * WW) / 256, 256, 0, stream>>>(poly, tbl);
        embed_mfma_kernel<true><<<N, 256, 0, stream>>>(x, tbl, poly, red, out);
    } else {
        embed_mfma_kernel<false><<<N, 256, 0, stream>>>(x, nullptr, poly, red, out);
    }
}

// Round 8
// 22.614 us; speedup vs baseline: 1.1883x; 1.1883x over previous
//
#include <hip/hip_runtime.h>
#include <hip/hip_bf16.h>
#include <hip/hip_fp16.h>

// N=4096, M=128, R=16, W=64, NG=1024, delta = 1/128 exactly.
// out[n,r,w] = sum_m red[n,r,m] * (c4[idx,w]*x0_m + c5[idx,w])
// Degree-1 truncation. f16 datapath: tbl = (f16(c4*delta), f16(c5)) pairs,
// embed = pk_fma(c4d_pair, f_pair, c5_pair) with f = fract(x*128).
// 2-n pipelined blocks, double-buffered LDS, single __syncthreads.

constexpr int MM = 128;
constexpr int RR = 16;
constexpr int WW = 64;
constexpr int NG = 1024;

using f32x4  = __attribute__((ext_vector_type(4))) float;
using f16x8  = __attribute__((ext_vector_type(8))) _Float16;

__device__ __forceinline__ unsigned pk_f16(float lo, float hi) {
    // v_cvt_pkrtz_f16_f32: result.lo = lo, result.hi = hi
    auto h = __builtin_amdgcn_cvt_pkrtz(lo, hi);
    unsigned r; __builtin_memcpy(&r, &h, 4); return r;
}

__device__ __forceinline__ unsigned fma2_f16(unsigned a, unsigned b, unsigned c) {
    __half2 ah, bh, ch;
    __builtin_memcpy(&ah, &a, 4); __builtin_memcpy(&bh, &b, 4); __builtin_memcpy(&ch, &c, 4);
    __half2 rh = __hfma2(ah, bh, ch);     // v_pk_fma_f16
    unsigned r; __builtin_memcpy(&r, &rh, 4); return r;
}

__device__ __forceinline__ unsigned u4c(const uint4& v, int c) {
    switch (c) { case 0: return v.x; case 1: return v.y; case 2: return v.z; default: return v.w; }
}

// ---- prepass: tbl[g*64 + w] = (f16(c5)<<16) | f16(c4 * delta) ----
__global__ __launch_bounds__(256)
void build_tbl_kernel(const float* __restrict__ poly, unsigned* __restrict__ tbl) {
    const int t = blockIdx.x * 256 + threadIdx.x;   // 65536
    const int g = t >> 6, w = t & 63;
    tbl[t] = pk_f16(poly[g * 384 + 256 + w] * 0.0078125f, poly[g * 384 + 320 + w]);
}

template<bool USE_TBL>
__global__ __launch_bounds__(256, 4)
void embed_mfma_kernel(const float* __restrict__ x,
                       const unsigned* __restrict__ tbl,
                       const float* __restrict__ poly,
                       const float* __restrict__ red,
                       float* __restrict__ out)
{
    // uint4 block b of a row = 8 consecutive k (m) as 4 f16-pairs; idx swizzled ^ (row&7).
    __shared__ uint4 eT[2][WW][16];   // 16 KB per buf (embed^T, f16)
    __shared__ uint4 rA[2][RR][16];   //  4 KB per buf (red, f16)     -> 40 KB total

    const int t    = threadIdx.x;
    const int c16  = t & 15;        // gather w-block / stage colblk / MFMA col & A-row
    const int mq   = t >> 4;        // gather+stage m-block (0..15)
    const int q    = mq & 3;        // lane>>4 within wave
    const int wt   = t >> 6;
    const int m0   = mq * 8;
    const size_t n0 = (size_t)blockIdx.x * 2;

    // ---------------- global loads for BOTH n up front ----------------
    const float* xp = x + n0 * MM + m0;
    const float4 xa0 = *(const float4*)xp;
    const float4 xb0 = *(const float4*)(xp + 4);
    const float4 xa1 = *(const float4*)(xp + MM);
    const float4 xb1 = *(const float4*)(xp + MM + 4);
    const float4* rv0 = (const float4*)(red + n0 * (RR * MM));
    const float4* rv1 = (const float4*)(red + (n0 + 1) * (RR * MM));
    const float4 ra0 = rv0[2 * t], rb0 = rv0[2 * t + 1];
    const float4 ra1 = rv1[2 * t], rb1 = rv1[2 * t + 1];

    // ---------------- idx/fract for both n ----------------
    auto prep = [&](const float4& xa, const float4& xb, int* ii, float* f) {
        const float xs[8] = {xa.x, xa.y, xa.z, xa.w, xb.x, xb.y, xb.z, xb.w};
#pragma unroll
        for (int j = 0; j < 8; ++j) {
            const float tt = xs[j] * 128.0f;       // exact (pow2)
            ii[j] = (int)tt;                       // trunc == floor (x >= 0)
            f[j]  = tt - (float)ii[j];             // exact fract; x0 = f*delta
        }
    };

    int ii0[8], ii1[8]; float f0[8], f1[8];
    uint4 g0[8], g1[8];

    prep(xa0, xb0, ii0, f0);
    if (USE_TBL) {
#pragma unroll
        for (int j = 0; j < 8; ++j)
            g0[j] = *(const uint4*)(tbl + (size_t)ii0[j] * 64 + c16 * 4);
    }
    prep(xa1, xb1, ii1, f1);
    if (USE_TBL) {
#pragma unroll
        for (int j = 0; j < 8; ++j)
            g1[j] = *(const uint4*)(tbl + (size_t)ii1[j] * 64 + c16 * 4);
    }

    // ---------------- staging ----------------
    auto stageA = [&](int buf, const float4& ra, const float4& rb) {
        // thread t holds red row mq, cols c16*8 .. +7 (coalesced load above)
        uint4 rp;
        rp.x = pk_f16(ra.x, ra.y); rp.y = pk_f16(ra.z, ra.w);
        rp.z = pk_f16(rb.x, rb.y); rp.w = pk_f16(rb.z, rb.w);
        rA[buf][mq][c16 ^ (mq & 7)] = rp;
    };

    auto stageB_tbl = [&](int buf, const uint4* g, const float* f) {
        unsigned f2[4];
#pragma unroll
        for (int jp = 0; jp < 4; ++jp) f2[jp] = pk_f16(f[2 * jp], f[2 * jp + 1]);
#pragma unroll
        for (int c = 0; c < 4; ++c) {
            const int w = c16 * 4 + c;
            unsigned e[4];
#pragma unroll
            for (int jp = 0; jp < 4; ++jp) {
                const unsigned ua = u4c(g[2 * jp], c);       // (c4d, c5) for m = m0+2jp
                const unsigned ub = u4c(g[2 * jp + 1], c);   // (c4d, c5) for m = m0+2jp+1
                const unsigned c4pk = (ua & 0xFFFFu) | (ub << 16);
                const unsigned c5pk = (ua >> 16) | (ub & 0xFFFF0000u);
                e[jp] = fma2_f16(c4pk, f2[jp], c5pk);        // (e_m, e_m1) f16 pair
            }
            uint4 v; v.x = e[0]; v.y = e[1]; v.z = e[2]; v.w = e[3];
            eT[buf][w][mq ^ (w & 7)] = v;
        }
    };

    auto stageB_raw = [&](int buf, const int* ii, const float* f) {
#pragma unroll
        for (int c = 0; c < 4; ++c) {
            const int w = c16 * 4 + c;
            unsigned e[4];
#pragma unroll
            for (int jp = 0; jp < 4; ++jp) {
                const float* pa = poly + (size_t)ii[2 * jp]     * 384 + 256 + c16 * 4;
                const float* pb = poly + (size_t)ii[2 * jp + 1] * 384 + 256 + c16 * 4;
                const float c4a = pa[c], c5a = pa[64 + c];
                const float c4b = pb[c], c5b = pb[64 + c];
                const float e0 = fmaf(c4a, f[2 * jp]     * 0.0078125f, c5a);
                const float e1 = fmaf(c4b, f[2 * jp + 1] * 0.0078125f, c5b);
                e[jp] = pk_f16(e0, e1);
            }
            uint4 v; v.x = e[0]; v.y = e[1]; v.z = e[2]; v.w = e[3];
            eT[buf][w][mq ^ (w & 7)] = v;
        }
    };

    // ---------------- MFMA + store ----------------
    auto mmad = [&](int buf, size_t n) {
        const int rowb = wt * 16 + c16;
        const int sa   = c16 & 7;            // == rowb & 7
        f32x4 acc = {0.f, 0.f, 0.f, 0.f};
#pragma unroll
        for (int kc = 0; kc < 4; ++kc) {
            const int bk = kc * 4 + q;
            const uint4 av = rA[buf][c16][bk ^ sa];
            const uint4 bv = eT[buf][rowb][bk ^ sa];
            f16x8 af, bf;
            __builtin_memcpy(&af, &av, 16);
            __builtin_memcpy(&bf, &bv, 16);
            acc = __builtin_amdgcn_mfma_f32_16x16x32_f16(af, bf, acc, 0, 0, 0);
        }
        // C/D layout: col = lane&15 (w), row = (lane>>4)*4 + reg (r)
        float* op = out + n * (RR * WW) + (size_t)(q * 4) * WW + rowb;
        op[0 * WW] = acc[0];
        op[1 * WW] = acc[1];
        op[2 * WW] = acc[2];
        op[3 * WW] = acc[3];
    };

    // ---------------- schedule: stage both, ONE sync, mfma both ----------------
    stageA(0, ra0, rb0);
    if (USE_TBL) stageB_tbl(0, g0, f0); else stageB_raw(0, ii0, f0);
    stageA(1, ra1, rb1);
    if (USE_TBL) stageB_tbl(1, g1, f1); else stageB_raw(1, ii1, f1);
    __syncthreads();
    mmad(0, n0);
    mmad(1, n0 + 1);
}

extern "C" void kernel_launch(void* const* d_in, const int* in_sizes, int n_in,
                              void* d_out, int out_size, void* d_ws, size_t ws_size,
                              hipStream_t stream) {
    const float* x    = (const float*)d_in[0];
    const float* poly = (const float*)d_in[1];
    const float* red  = (const float*)d_in[2];
    float* out = (float*)d_out;
    const int N = in_sizes[0] / MM;   // 4096

    if (ws_size >= (size_t)(NG * WW * sizeof(unsigned))) {
        unsigned* tbl = (unsigned*)d_ws;
        build_tbl_kernel<<<(NG * WW) / 256, 256, 0, stream>>>(poly, tbl);
        embed_mfma_kernel<true><<<N / 2, 256, 0, stream>>>(x, tbl, poly, red, out);
    } else {
        embed_mfma_kernel<false><<<N / 2, 256, 0, stream>>>(x, nullptr, poly, red, out);
    }
}